// Round 11
// baseline (260.494 us; speedup 1.0000x reference)
//
#include <hip/hip_runtime.h>
#include <hip/hip_fp16.h>

#define BB 16
#define HH 512
#define WW 512
#define NVV 35709
#define NTT 70000
#define HWW (HH * WW)
#define NVTOT (BB * NVV)          // 571344, divisible by 4

// World model (R0-R10, verified):
//   proj_geo, texture, nbl, ori_img : float32
//   is_visible, tri_inds, pixel_valid : int32
//   OUTPUT: float32, concatenated [render BHW3 | real BHW3]
//
// R10 post-mortem: prep+splat ~7us; compose is everything else and is
// latency/residency-bound (49MB FETCH / 160MB WRITE in ~73us, VALU 7%).
// R9 proved occupancy dominates this kernel (11% occ -> 3.2x slower).
// R11: compose at exactly-full residency: 8px/thread, 2048 blocks
// (8 blocks/CU x 4 waves = 32 waves/CU, one wave-generation), cached
// loads, NT stores, single dispatch.
//
// ws layout: VRec shw[NVTOT] (16 B/vertex: f32 x, f32 y, f16 rg, f16 b|vis)
//            __half2 acc[nb*HW*2] (8 B/pixel: (r,g),(b,w))

typedef float fvec4 __attribute__((ext_vector_type(4)));

struct VRec { float x, y; __half2 rg; __half2 bv; };   // 16 B

__device__ inline void pk_add(__half2* p, __half2 v)
{
    unsafeAtomicAdd(p, v);   // global_atomic_pk_add_f16 on gfx950
}

// ---------------------------------------------------------------------------
// prep: grid-stride. (a) zero acc region, (b) build 16B vertex records.
// Positions copied bit-exact f32; colors tex*nbl rounded to f16.
// ---------------------------------------------------------------------------
__global__ __launch_bounds__(256) void prep_kernel(
    const float4* __restrict__ proj4,
    const float4* __restrict__ tex4,
    const float4* __restrict__ nbl4,
    const int4* __restrict__ vis4,
    fvec4* __restrict__ shwv,
    float4* __restrict__ accz, long accN4)
{
    long tid = (long)blockIdx.x * blockDim.x + threadIdx.x;
    long stride = (long)gridDim.x * blockDim.x;

    float4 z = {0.f, 0.f, 0.f, 0.f};
    for (long i = tid; i < accN4; i += stride) accz[i] = z;

    for (long q = tid; q < NVTOT / 4; q += stride) {
        float4 P0 = proj4[q * 3 + 0], P1 = proj4[q * 3 + 1], P2 = proj4[q * 3 + 2];
        float4 T0 = tex4[q * 3 + 0], T1 = tex4[q * 3 + 1], T2 = tex4[q * 3 + 2];
        float4 N0 = nbl4[q * 3 + 0], N1 = nbl4[q * 3 + 1], N2 = nbl4[q * 3 + 2];
        int4 V = vis4[q];

        VRec r0, r1, r2, r3;
        r0.x = P0.x; r0.y = P0.y;
        r0.rg = __floats2half2_rn(T0.x * N0.x, T0.y * N0.y);
        r0.bv = __floats2half2_rn(T0.z * N0.z, V.x ? 1.f : 0.f);
        r1.x = P0.w; r1.y = P1.x;
        r1.rg = __floats2half2_rn(T0.w * N0.w, T1.x * N1.x);
        r1.bv = __floats2half2_rn(T1.y * N1.y, V.y ? 1.f : 0.f);
        r2.x = P1.z; r2.y = P1.w;
        r2.rg = __floats2half2_rn(T1.z * N1.z, T1.w * N1.w);
        r2.bv = __floats2half2_rn(T2.x * N2.x, V.z ? 1.f : 0.f);
        r3.x = P2.y; r3.y = P2.z;
        r3.rg = __floats2half2_rn(T2.y * N2.y, T2.z * N2.z);
        r3.bv = __floats2half2_rn(T2.w * N2.w, V.w ? 1.f : 0.f);

        shwv[q * 4 + 0] = __builtin_bit_cast(fvec4, r0);
        shwv[q * 4 + 1] = __builtin_bit_cast(fvec4, r1);
        shwv[q * 4 + 2] = __builtin_bit_cast(fvec4, r2);
        shwv[q * 4 + 3] = __builtin_bit_cast(fvec4, r3);
    }
}

// ---------------------------------------------------------------------------
// splat: 4 triangles/thread. 3 int4 index loads + 12 x 16B record gathers
// (all issued up front for MLP), then per-tri vis gate + centroid + 2 atomics.
// ---------------------------------------------------------------------------
__global__ __launch_bounds__(256) void splat_kernel(
    const fvec4* __restrict__ shwv,
    const int4* __restrict__ tri4,    // [NTT*3/4]
    __half2* __restrict__ acc,
    int b0)
{
    int g = blockIdx.x * blockDim.x + threadIdx.x;   // 4-triangle group
    if (g >= NTT / 4) return;                        // 17500 groups
    int bl = blockIdx.y;
    int base = (b0 + bl) * NVV;

    int4 wA = tri4[g * 3 + 0];
    int4 wB = tri4[g * 3 + 1];
    int4 wC = tri4[g * 3 + 2];
    int idx[12] = {wA.x, wA.y, wA.z, wA.w, wB.x, wB.y, wB.z, wB.w,
                   wC.x, wC.y, wC.z, wC.w};

    fvec4 vr[12];
#pragma unroll
    for (int k = 0; k < 12; ++k) vr[k] = shwv[base + idx[k]];

    long paccb = (long)bl * HWW;
#pragma unroll
    for (int k = 0; k < 4; ++k) {
        VRec s0 = __builtin_bit_cast(VRec, vr[k * 3 + 0]);
        VRec s1 = __builtin_bit_cast(VRec, vr[k * 3 + 1]);
        VRec s2 = __builtin_bit_cast(VRec, vr[k * 3 + 2]);

        // tri_w = min(vis): any invisible vertex kills the splat
        if (__high2float(s0.bv) == 0.f || __high2float(s1.bv) == 0.f ||
            __high2float(s2.bv) == 0.f) continue;

        float fx = ((s0.x + s1.x) + s2.x) / 3.0f;   // numpy f32 semantics
        float fy = ((s0.y + s1.y) + s2.y) / 3.0f;
        int px = (int)rintf(fx);                    // round-half-even
        int py = (int)rintf(fy);
        px = min(max(px, 0), WW - 1);
        py = min(max(py, 0), HH - 1);

        float cr = ((__low2float(s0.rg) + __low2float(s1.rg)) + __low2float(s2.rg)) / 3.0f;
        float cg = ((__high2float(s0.rg) + __high2float(s1.rg)) + __high2float(s2.rg)) / 3.0f;
        float cb = ((__low2float(s0.bv) + __low2float(s1.bv)) + __low2float(s2.bv)) / 3.0f;

        long lin = paccb + (long)py * WW + px;
        pk_add(&acc[lin * 2 + 0], __floats2half2_rn(cr, cg));
        pk_add(&acc[lin * 2 + 1], __floats2half2_rn(cb, 1.0f));
    }
}

// ---------------------------------------------------------------------------
// compose: 8 pixels/thread, exactly-resident grid (2048 blocks for nb=16).
// Cached loads (ori/pv/acc), NT stores (outputs are write-once streams).
// ---------------------------------------------------------------------------
__device__ inline float2 unpack_h2(float w)
{
    __half2 h = __builtin_bit_cast(__half2, w);
    return make_float2(__low2float(h), __high2float(h));
}

__global__ __launch_bounds__(256) void compose_kernel(
    const float4* __restrict__ accv,
    const float4* __restrict__ oriv,
    const int4* __restrict__ pvv,
    fvec4* __restrict__ outv,
    int b0, int nb)
{
    long l = (long)blockIdx.x * blockDim.x + threadIdx.x;   // local 8-px group
    long ngrp = (long)nb * (HWW / 8);
    if (l >= ngrp) return;
    long gg = (long)b0 * (HWW / 8) + l;                     // global group

    // acc: 4 x float4 = 8 pixels (2 px per float4)
    float4 A0 = accv[l * 4 + 0];
    float4 A1 = accv[l * 4 + 1];
    float4 A2 = accv[l * 4 + 2];
    float4 A3 = accv[l * 4 + 3];
    int4 PV0 = pvv[gg * 2 + 0];
    int4 PV1 = pvv[gg * 2 + 1];
    float4 O0 = oriv[gg * 6 + 0];
    float4 O1 = oriv[gg * 6 + 1];
    float4 O2 = oriv[gg * 6 + 2];
    float4 O3 = oriv[gg * 6 + 3];
    float4 O4 = oriv[gg * 6 + 4];
    float4 O5 = oriv[gg * 6 + 5];

    float of[24] = {O0.x, O0.y, O0.z, O0.w, O1.x, O1.y, O1.z, O1.w,
                    O2.x, O2.y, O2.z, O2.w, O3.x, O3.y, O3.z, O3.w,
                    O4.x, O4.y, O4.z, O4.w, O5.x, O5.y, O5.z, O5.w};
    float2 rg[8], bw[8];
    rg[0] = unpack_h2(A0.x); bw[0] = unpack_h2(A0.y);
    rg[1] = unpack_h2(A0.z); bw[1] = unpack_h2(A0.w);
    rg[2] = unpack_h2(A1.x); bw[2] = unpack_h2(A1.y);
    rg[3] = unpack_h2(A1.z); bw[3] = unpack_h2(A1.w);
    rg[4] = unpack_h2(A2.x); bw[4] = unpack_h2(A2.y);
    rg[5] = unpack_h2(A2.z); bw[5] = unpack_h2(A2.w);
    rg[6] = unpack_h2(A3.x); bw[6] = unpack_h2(A3.y);
    rg[7] = unpack_h2(A3.z); bw[7] = unpack_h2(A3.w);
    int pva[8] = {PV0.x, PV0.y, PV0.z, PV0.w, PV1.x, PV1.y, PV1.z, PV1.w};

    float rd[24], rl[24];
#pragma unroll
    for (int p = 0; p < 8; ++p) {
        float w = bw[p].y;
        bool pv = pva[p] > 0;
        bool cov = (w > 0.f) && pv;
        float dn = fmaxf(w, 1.f);
        rd[p * 3 + 0] = cov ? rg[p].x / dn : of[p * 3 + 0];
        rd[p * 3 + 1] = cov ? rg[p].y / dn : of[p * 3 + 1];
        rd[p * 3 + 2] = cov ? bw[p].x / dn : of[p * 3 + 2];
        rl[p * 3 + 0] = pv ? of[p * 3 + 0] : 0.f;
        rl[p * 3 + 1] = pv ? of[p * 3 + 1] : 0.f;
        rl[p * 3 + 2] = pv ? of[p * 3 + 2] : 0.f;
    }

    const long RO4 = (long)BB * HWW * 3 / 4;   // `real` offset in fvec4 units
#pragma unroll
    for (int j = 0; j < 6; ++j) {
        fvec4 R = {rd[j * 4 + 0], rd[j * 4 + 1], rd[j * 4 + 2], rd[j * 4 + 3]};
        fvec4 L = {rl[j * 4 + 0], rl[j * 4 + 1], rl[j * 4 + 2], rl[j * 4 + 3]};
        __builtin_nontemporal_store(R, &outv[gg * 6 + j]);
        __builtin_nontemporal_store(L, &outv[RO4 + gg * 6 + j]);
    }
}

extern "C" void kernel_launch(void* const* d_in, const int* in_sizes, int n_in,
                              void* d_out, int out_size, void* d_ws, size_t ws_size,
                              hipStream_t stream) {
    const float* proj = (const float*)d_in[0];
    const float* tex  = (const float*)d_in[1];
    const float* nbl  = (const float*)d_in[2];
    const float* ori  = (const float*)d_in[3];
    const int* vis    = (const int*)d_in[4];
    const int* tri    = (const int*)d_in[5];
    const int* pvalid = (const int*)d_in[6];
    float* out        = (float*)d_out;

    const size_t SHBYTES = (size_t)NVTOT * 16;         // 9.14 MB, 16B-aligned
    fvec4* shwv = (fvec4*)d_ws;
    char* accBase = (char*)d_ws + SHBYTES;

    const size_t perBatchBytes = (size_t)HWW * 8;      // 2 MiB / batch
    size_t remain = (ws_size > SHBYTES) ? ws_size - SHBYTES : 0;
    int nbMax = (int)(remain / perBatchBytes);
    if (nbMax < 1) nbMax = 1;
    if (nbMax > BB) nbMax = BB;

    for (int b0 = 0; b0 < BB; b0 += nbMax) {
        int nb = (BB - b0 < nbMax) ? (BB - b0) : nbMax;
        __half2* acc = (__half2*)accBase;

        long accN4 = (long)nb * HWW / 2;               // float4s to zero
        prep_kernel<<<2048, 256, 0, stream>>>(
            (const float4*)proj, (const float4*)tex, (const float4*)nbl,
            (const int4*)vis, shwv, (float4*)accBase, accN4);

        dim3 gs((NTT / 4 + 255) / 256, nb);
        splat_kernel<<<gs, 256, 0, stream>>>(shwv, (const int4*)tri, acc, b0);

        long ngrp8 = (long)nb * (HWW / 8);             // 8 px per thread
        int blocks = (int)((ngrp8 + 255) / 256);       // 2048 for nb=16
        compose_kernel<<<blocks, 256, 0, stream>>>(
            (const float4*)accBase, (const float4*)ori, (const int4*)pvalid,
            (fvec4*)out, b0, nb);
    }
}

// Round 12
// 95.856 us; speedup vs baseline: 2.7176x; 2.7176x over previous
//
#include <hip/hip_runtime.h>
#include <hip/hip_fp16.h>

#define BB 16
#define HH 512
#define WW 512
#define NVV 35709
#define NTT 70000
#define HWW (HH * WW)
#define NVTOT (BB * NVV)          // 571344, divisible by 4

// World model (R0-R11, verified):
//   proj_geo, texture, nbl, ori_img : float32
//   is_visible, tri_inds, pixel_valid : int32
//   OUTPUT: float32, concatenated [render BHW3 | real BHW3]
//
// R11 post-mortem: 8px compose = scratch spill (VGPR 32, +185MB scratch
// writes, 240us) -- also retro-explains R9. Proven body is the 4px one-shot
// (VGPR 20-24). R12: same 4px body, grid-stride loop (2048 blocks),
// copy-kernel structure for wave-pipelined loads/stores.
//
// ws layout: VRec shw[NVTOT] (16 B/vertex: f32 x, f32 y, f16 rg, f16 b|vis)
//            __half2 acc[nb*HW*2] (8 B/pixel: (r,g),(b,w))

typedef float fvec4 __attribute__((ext_vector_type(4)));

struct VRec { float x, y; __half2 rg; __half2 bv; };   // 16 B

__device__ inline void pk_add(__half2* p, __half2 v)
{
    unsafeAtomicAdd(p, v);   // global_atomic_pk_add_f16 on gfx950
}

// ---------------------------------------------------------------------------
// prep: grid-stride. (a) zero acc region, (b) build 16B vertex records.
// Positions copied bit-exact f32; colors tex*nbl rounded to f16.
// ---------------------------------------------------------------------------
__global__ __launch_bounds__(256) void prep_kernel(
    const float4* __restrict__ proj4,
    const float4* __restrict__ tex4,
    const float4* __restrict__ nbl4,
    const int4* __restrict__ vis4,
    fvec4* __restrict__ shwv,
    float4* __restrict__ accz, long accN4)
{
    long tid = (long)blockIdx.x * blockDim.x + threadIdx.x;
    long stride = (long)gridDim.x * blockDim.x;

    float4 z = {0.f, 0.f, 0.f, 0.f};
    for (long i = tid; i < accN4; i += stride) accz[i] = z;

    for (long q = tid; q < NVTOT / 4; q += stride) {
        float4 P0 = proj4[q * 3 + 0], P1 = proj4[q * 3 + 1], P2 = proj4[q * 3 + 2];
        float4 T0 = tex4[q * 3 + 0], T1 = tex4[q * 3 + 1], T2 = tex4[q * 3 + 2];
        float4 N0 = nbl4[q * 3 + 0], N1 = nbl4[q * 3 + 1], N2 = nbl4[q * 3 + 2];
        int4 V = vis4[q];

        VRec r0, r1, r2, r3;
        r0.x = P0.x; r0.y = P0.y;
        r0.rg = __floats2half2_rn(T0.x * N0.x, T0.y * N0.y);
        r0.bv = __floats2half2_rn(T0.z * N0.z, V.x ? 1.f : 0.f);
        r1.x = P0.w; r1.y = P1.x;
        r1.rg = __floats2half2_rn(T0.w * N0.w, T1.x * N1.x);
        r1.bv = __floats2half2_rn(T1.y * N1.y, V.y ? 1.f : 0.f);
        r2.x = P1.z; r2.y = P1.w;
        r2.rg = __floats2half2_rn(T1.z * N1.z, T1.w * N1.w);
        r2.bv = __floats2half2_rn(T2.x * N2.x, V.z ? 1.f : 0.f);
        r3.x = P2.y; r3.y = P2.z;
        r3.rg = __floats2half2_rn(T2.y * N2.y, T2.z * N2.z);
        r3.bv = __floats2half2_rn(T2.w * N2.w, V.w ? 1.f : 0.f);

        shwv[q * 4 + 0] = __builtin_bit_cast(fvec4, r0);
        shwv[q * 4 + 1] = __builtin_bit_cast(fvec4, r1);
        shwv[q * 4 + 2] = __builtin_bit_cast(fvec4, r2);
        shwv[q * 4 + 3] = __builtin_bit_cast(fvec4, r3);
    }
}

// ---------------------------------------------------------------------------
// splat: 4 triangles/thread. 3 int4 index loads + 12 x 16B record gathers
// (all issued up front for MLP), then per-tri vis gate + centroid + 2 atomics.
// ---------------------------------------------------------------------------
__global__ __launch_bounds__(256) void splat_kernel(
    const fvec4* __restrict__ shwv,
    const int4* __restrict__ tri4,    // [NTT*3/4]
    __half2* __restrict__ acc,
    int b0)
{
    int g = blockIdx.x * blockDim.x + threadIdx.x;   // 4-triangle group
    if (g >= NTT / 4) return;                        // 17500 groups
    int bl = blockIdx.y;
    int base = (b0 + bl) * NVV;

    int4 wA = tri4[g * 3 + 0];
    int4 wB = tri4[g * 3 + 1];
    int4 wC = tri4[g * 3 + 2];
    int idx[12] = {wA.x, wA.y, wA.z, wA.w, wB.x, wB.y, wB.z, wB.w,
                   wC.x, wC.y, wC.z, wC.w};

    fvec4 vr[12];
#pragma unroll
    for (int k = 0; k < 12; ++k) vr[k] = shwv[base + idx[k]];

    long paccb = (long)bl * HWW;
#pragma unroll
    for (int k = 0; k < 4; ++k) {
        VRec s0 = __builtin_bit_cast(VRec, vr[k * 3 + 0]);
        VRec s1 = __builtin_bit_cast(VRec, vr[k * 3 + 1]);
        VRec s2 = __builtin_bit_cast(VRec, vr[k * 3 + 2]);

        // tri_w = min(vis): any invisible vertex kills the splat
        if (__high2float(s0.bv) == 0.f || __high2float(s1.bv) == 0.f ||
            __high2float(s2.bv) == 0.f) continue;

        float fx = ((s0.x + s1.x) + s2.x) / 3.0f;   // numpy f32 semantics
        float fy = ((s0.y + s1.y) + s2.y) / 3.0f;
        int px = (int)rintf(fx);                    // round-half-even
        int py = (int)rintf(fy);
        px = min(max(px, 0), WW - 1);
        py = min(max(py, 0), HH - 1);

        float cr = ((__low2float(s0.rg) + __low2float(s1.rg)) + __low2float(s2.rg)) / 3.0f;
        float cg = ((__high2float(s0.rg) + __high2float(s1.rg)) + __high2float(s2.rg)) / 3.0f;
        float cb = ((__low2float(s0.bv) + __low2float(s1.bv)) + __low2float(s2.bv)) / 3.0f;

        long lin = paccb + (long)py * WW + px;
        pk_add(&acc[lin * 2 + 0], __floats2half2_rn(cr, cg));
        pk_add(&acc[lin * 2 + 1], __floats2half2_rn(cb, 1.0f));
    }
}

// ---------------------------------------------------------------------------
// compose: proven 4px body, grid-stride loop (copy-kernel structure).
// Cached loads, NT stores. 2048 blocks x 256 threads = full residency;
// ~8 iterations/thread pipelines loads of iter i+1 against stores of i.
// ---------------------------------------------------------------------------
__device__ inline float2 unpack_h2(float w)
{
    __half2 h = __builtin_bit_cast(__half2, w);
    return make_float2(__low2float(h), __high2float(h));
}

__global__ __launch_bounds__(256) void compose_kernel(
    const float4* __restrict__ accv,     // local (pass) accumulator as float4
    const float4* __restrict__ oriv,
    const int4* __restrict__ pvv,
    fvec4* __restrict__ outv,
    int b0, int nb)
{
    long ngrp = (long)nb * (HWW / 4);
    long stride = (long)gridDim.x * blockDim.x;
    const long RO4 = (long)BB * HWW * 3 / 4;   // `real` offset in fvec4 units

    for (long q = (long)blockIdx.x * blockDim.x + threadIdx.x; q < ngrp;
         q += stride) {
        long qg = (long)b0 * (HWW / 4) + q;                 // global group

        float4 A0 = accv[q * 2 + 0];   // pixels 0,1: (rg,bw),(rg,bw)
        float4 A1 = accv[q * 2 + 1];   // pixels 2,3
        int4 PV = pvv[qg];
        float4 O0 = oriv[qg * 3 + 0];
        float4 O1 = oriv[qg * 3 + 1];
        float4 O2 = oriv[qg * 3 + 2];

        float of[12] = {O0.x, O0.y, O0.z, O0.w, O1.x, O1.y, O1.z, O1.w,
                        O2.x, O2.y, O2.z, O2.w};
        float2 rg[4], bw[4];
        rg[0] = unpack_h2(A0.x); bw[0] = unpack_h2(A0.y);
        rg[1] = unpack_h2(A0.z); bw[1] = unpack_h2(A0.w);
        rg[2] = unpack_h2(A1.x); bw[2] = unpack_h2(A1.y);
        rg[3] = unpack_h2(A1.z); bw[3] = unpack_h2(A1.w);
        int pva[4] = {PV.x, PV.y, PV.z, PV.w};

        float rd[12], rl[12];
#pragma unroll
        for (int p = 0; p < 4; ++p) {
            float w = bw[p].y;
            bool pv = pva[p] > 0;
            bool cov = (w > 0.f) && pv;
            float dn = fmaxf(w, 1.f);
            rd[p * 3 + 0] = cov ? rg[p].x / dn : of[p * 3 + 0];
            rd[p * 3 + 1] = cov ? rg[p].y / dn : of[p * 3 + 1];
            rd[p * 3 + 2] = cov ? bw[p].x / dn : of[p * 3 + 2];
            rl[p * 3 + 0] = pv ? of[p * 3 + 0] : 0.f;
            rl[p * 3 + 1] = pv ? of[p * 3 + 1] : 0.f;
            rl[p * 3 + 2] = pv ? of[p * 3 + 2] : 0.f;
        }

        fvec4 R0 = {rd[0], rd[1], rd[2], rd[3]};
        fvec4 R1 = {rd[4], rd[5], rd[6], rd[7]};
        fvec4 R2 = {rd[8], rd[9], rd[10], rd[11]};
        fvec4 L0 = {rl[0], rl[1], rl[2], rl[3]};
        fvec4 L1 = {rl[4], rl[5], rl[6], rl[7]};
        fvec4 L2 = {rl[8], rl[9], rl[10], rl[11]};
        __builtin_nontemporal_store(R0, &outv[qg * 3 + 0]);
        __builtin_nontemporal_store(R1, &outv[qg * 3 + 1]);
        __builtin_nontemporal_store(R2, &outv[qg * 3 + 2]);
        __builtin_nontemporal_store(L0, &outv[RO4 + qg * 3 + 0]);
        __builtin_nontemporal_store(L1, &outv[RO4 + qg * 3 + 1]);
        __builtin_nontemporal_store(L2, &outv[RO4 + qg * 3 + 2]);
    }
}

extern "C" void kernel_launch(void* const* d_in, const int* in_sizes, int n_in,
                              void* d_out, int out_size, void* d_ws, size_t ws_size,
                              hipStream_t stream) {
    const float* proj = (const float*)d_in[0];
    const float* tex  = (const float*)d_in[1];
    const float* nbl  = (const float*)d_in[2];
    const float* ori  = (const float*)d_in[3];
    const int* vis    = (const int*)d_in[4];
    const int* tri    = (const int*)d_in[5];
    const int* pvalid = (const int*)d_in[6];
    float* out        = (float*)d_out;

    const size_t SHBYTES = (size_t)NVTOT * 16;         // 9.14 MB, 16B-aligned
    fvec4* shwv = (fvec4*)d_ws;
    char* accBase = (char*)d_ws + SHBYTES;

    const size_t perBatchBytes = (size_t)HWW * 8;      // 2 MiB / batch
    size_t remain = (ws_size > SHBYTES) ? ws_size - SHBYTES : 0;
    int nbMax = (int)(remain / perBatchBytes);
    if (nbMax < 1) nbMax = 1;
    if (nbMax > BB) nbMax = BB;

    for (int b0 = 0; b0 < BB; b0 += nbMax) {
        int nb = (BB - b0 < nbMax) ? (BB - b0) : nbMax;
        __half2* acc = (__half2*)accBase;

        long accN4 = (long)nb * HWW / 2;               // float4s to zero
        prep_kernel<<<2048, 256, 0, stream>>>(
            (const float4*)proj, (const float4*)tex, (const float4*)nbl,
            (const int4*)vis, shwv, (float4*)accBase, accN4);

        dim3 gs((NTT / 4 + 255) / 256, nb);
        splat_kernel<<<gs, 256, 0, stream>>>(shwv, (const int4*)tri, acc, b0);

        compose_kernel<<<2048, 256, 0, stream>>>(
            (const float4*)accBase, (const float4*)ori, (const int4*)pvalid,
            (fvec4*)out, b0, nb);
    }
}

// Round 13
// 79.422 us; speedup vs baseline: 3.2799x; 1.2069x over previous
//
#include <hip/hip_runtime.h>
#include <hip/hip_fp16.h>

#define BB 16
#define HH 512
#define WW 512
#define NVV 35709
#define NTT 70000
#define HWW (HH * WW)
#define NVTOT (BB * NVV)          // 571344, divisible by 4

// World model (R0-R12, verified):
//   proj_geo, texture, nbl, ori_img : float32
//   is_visible, tri_inds, pixel_valid : int32
//   OUTPUT: float32, concatenated [render BHW3 | real BHW3]
//
// R12 post-mortem: grid-stride neutral (compose 73-76us both one-shot and
// strided). Cross-round datum: R5's scalar REGULAR-store compose ran <57us
// (absent from a top-5 floored at 57us) with MORE logical traffic. NT stores
// (introduced R7) force the 201MB output stream to drain to HBM inside the
// dispatch (no L3 write-back absorption; output fits in 256MB L3).
// R13: plain cached float4 stores in compose. Everything else identical.
//
// ws layout: VRec shw[NVTOT] (16 B/vertex: f32 x, f32 y, f16 rg, f16 b|vis)
//            __half2 acc[nb*HW*2] (8 B/pixel: (r,g),(b,w))

typedef float fvec4 __attribute__((ext_vector_type(4)));

struct VRec { float x, y; __half2 rg; __half2 bv; };   // 16 B

__device__ inline void pk_add(__half2* p, __half2 v)
{
    unsafeAtomicAdd(p, v);   // global_atomic_pk_add_f16 on gfx950
}

// ---------------------------------------------------------------------------
// prep: grid-stride. (a) zero acc region, (b) build 16B vertex records.
// Positions copied bit-exact f32; colors tex*nbl rounded to f16.
// ---------------------------------------------------------------------------
__global__ __launch_bounds__(256) void prep_kernel(
    const float4* __restrict__ proj4,
    const float4* __restrict__ tex4,
    const float4* __restrict__ nbl4,
    const int4* __restrict__ vis4,
    fvec4* __restrict__ shwv,
    float4* __restrict__ accz, long accN4)
{
    long tid = (long)blockIdx.x * blockDim.x + threadIdx.x;
    long stride = (long)gridDim.x * blockDim.x;

    float4 z = {0.f, 0.f, 0.f, 0.f};
    for (long i = tid; i < accN4; i += stride) accz[i] = z;

    for (long q = tid; q < NVTOT / 4; q += stride) {
        float4 P0 = proj4[q * 3 + 0], P1 = proj4[q * 3 + 1], P2 = proj4[q * 3 + 2];
        float4 T0 = tex4[q * 3 + 0], T1 = tex4[q * 3 + 1], T2 = tex4[q * 3 + 2];
        float4 N0 = nbl4[q * 3 + 0], N1 = nbl4[q * 3 + 1], N2 = nbl4[q * 3 + 2];
        int4 V = vis4[q];

        VRec r0, r1, r2, r3;
        r0.x = P0.x; r0.y = P0.y;
        r0.rg = __floats2half2_rn(T0.x * N0.x, T0.y * N0.y);
        r0.bv = __floats2half2_rn(T0.z * N0.z, V.x ? 1.f : 0.f);
        r1.x = P0.w; r1.y = P1.x;
        r1.rg = __floats2half2_rn(T0.w * N0.w, T1.x * N1.x);
        r1.bv = __floats2half2_rn(T1.y * N1.y, V.y ? 1.f : 0.f);
        r2.x = P1.z; r2.y = P1.w;
        r2.rg = __floats2half2_rn(T1.z * N1.z, T1.w * N1.w);
        r2.bv = __floats2half2_rn(T2.x * N2.x, V.z ? 1.f : 0.f);
        r3.x = P2.y; r3.y = P2.z;
        r3.rg = __floats2half2_rn(T2.y * N2.y, T2.z * N2.z);
        r3.bv = __floats2half2_rn(T2.w * N2.w, V.w ? 1.f : 0.f);

        shwv[q * 4 + 0] = __builtin_bit_cast(fvec4, r0);
        shwv[q * 4 + 1] = __builtin_bit_cast(fvec4, r1);
        shwv[q * 4 + 2] = __builtin_bit_cast(fvec4, r2);
        shwv[q * 4 + 3] = __builtin_bit_cast(fvec4, r3);
    }
}

// ---------------------------------------------------------------------------
// splat: 4 triangles/thread. 3 int4 index loads + 12 x 16B record gathers
// (all issued up front for MLP), then per-tri vis gate + centroid + 2 atomics.
// ---------------------------------------------------------------------------
__global__ __launch_bounds__(256) void splat_kernel(
    const fvec4* __restrict__ shwv,
    const int4* __restrict__ tri4,    // [NTT*3/4]
    __half2* __restrict__ acc,
    int b0)
{
    int g = blockIdx.x * blockDim.x + threadIdx.x;   // 4-triangle group
    if (g >= NTT / 4) return;                        // 17500 groups
    int bl = blockIdx.y;
    int base = (b0 + bl) * NVV;

    int4 wA = tri4[g * 3 + 0];
    int4 wB = tri4[g * 3 + 1];
    int4 wC = tri4[g * 3 + 2];
    int idx[12] = {wA.x, wA.y, wA.z, wA.w, wB.x, wB.y, wB.z, wB.w,
                   wC.x, wC.y, wC.z, wC.w};

    fvec4 vr[12];
#pragma unroll
    for (int k = 0; k < 12; ++k) vr[k] = shwv[base + idx[k]];

    long paccb = (long)bl * HWW;
#pragma unroll
    for (int k = 0; k < 4; ++k) {
        VRec s0 = __builtin_bit_cast(VRec, vr[k * 3 + 0]);
        VRec s1 = __builtin_bit_cast(VRec, vr[k * 3 + 1]);
        VRec s2 = __builtin_bit_cast(VRec, vr[k * 3 + 2]);

        // tri_w = min(vis): any invisible vertex kills the splat
        if (__high2float(s0.bv) == 0.f || __high2float(s1.bv) == 0.f ||
            __high2float(s2.bv) == 0.f) continue;

        float fx = ((s0.x + s1.x) + s2.x) / 3.0f;   // numpy f32 semantics
        float fy = ((s0.y + s1.y) + s2.y) / 3.0f;
        int px = (int)rintf(fx);                    // round-half-even
        int py = (int)rintf(fy);
        px = min(max(px, 0), WW - 1);
        py = min(max(py, 0), HH - 1);

        float cr = ((__low2float(s0.rg) + __low2float(s1.rg)) + __low2float(s2.rg)) / 3.0f;
        float cg = ((__high2float(s0.rg) + __high2float(s1.rg)) + __high2float(s2.rg)) / 3.0f;
        float cb = ((__low2float(s0.bv) + __low2float(s1.bv)) + __low2float(s2.bv)) / 3.0f;

        long lin = paccb + (long)py * WW + px;
        pk_add(&acc[lin * 2 + 0], __floats2half2_rn(cr, cg));
        pk_add(&acc[lin * 2 + 1], __floats2half2_rn(cb, 1.0f));
    }
}

// ---------------------------------------------------------------------------
// compose: 4px/thread grid-stride, cached loads, PLAIN cached float4 stores
// (output fits L3 -> write-back absorbs the stream; NT forced in-dispatch
// HBM drain, the R7-R12 regression).
// ---------------------------------------------------------------------------
__device__ inline float2 unpack_h2(float w)
{
    __half2 h = __builtin_bit_cast(__half2, w);
    return make_float2(__low2float(h), __high2float(h));
}

__global__ __launch_bounds__(256) void compose_kernel(
    const float4* __restrict__ accv,     // local (pass) accumulator as float4
    const float4* __restrict__ oriv,
    const int4* __restrict__ pvv,
    float4* __restrict__ outv,
    int b0, int nb)
{
    long ngrp = (long)nb * (HWW / 4);
    long stride = (long)gridDim.x * blockDim.x;
    const long RO4 = (long)BB * HWW * 3 / 4;   // `real` offset in float4 units

    for (long q = (long)blockIdx.x * blockDim.x + threadIdx.x; q < ngrp;
         q += stride) {
        long qg = (long)b0 * (HWW / 4) + q;                 // global group

        float4 A0 = accv[q * 2 + 0];   // pixels 0,1: (rg,bw),(rg,bw)
        float4 A1 = accv[q * 2 + 1];   // pixels 2,3
        int4 PV = pvv[qg];
        float4 O0 = oriv[qg * 3 + 0];
        float4 O1 = oriv[qg * 3 + 1];
        float4 O2 = oriv[qg * 3 + 2];

        float of[12] = {O0.x, O0.y, O0.z, O0.w, O1.x, O1.y, O1.z, O1.w,
                        O2.x, O2.y, O2.z, O2.w};
        float2 rg[4], bw[4];
        rg[0] = unpack_h2(A0.x); bw[0] = unpack_h2(A0.y);
        rg[1] = unpack_h2(A0.z); bw[1] = unpack_h2(A0.w);
        rg[2] = unpack_h2(A1.x); bw[2] = unpack_h2(A1.y);
        rg[3] = unpack_h2(A1.z); bw[3] = unpack_h2(A1.w);
        int pva[4] = {PV.x, PV.y, PV.z, PV.w};

        float rd[12], rl[12];
#pragma unroll
        for (int p = 0; p < 4; ++p) {
            float w = bw[p].y;
            bool pv = pva[p] > 0;
            bool cov = (w > 0.f) && pv;
            float dn = fmaxf(w, 1.f);
            rd[p * 3 + 0] = cov ? rg[p].x / dn : of[p * 3 + 0];
            rd[p * 3 + 1] = cov ? rg[p].y / dn : of[p * 3 + 1];
            rd[p * 3 + 2] = cov ? bw[p].x / dn : of[p * 3 + 2];
            rl[p * 3 + 0] = pv ? of[p * 3 + 0] : 0.f;
            rl[p * 3 + 1] = pv ? of[p * 3 + 1] : 0.f;
            rl[p * 3 + 2] = pv ? of[p * 3 + 2] : 0.f;
        }

        float4 R0 = {rd[0], rd[1], rd[2], rd[3]};
        float4 R1 = {rd[4], rd[5], rd[6], rd[7]};
        float4 R2 = {rd[8], rd[9], rd[10], rd[11]};
        float4 L0 = {rl[0], rl[1], rl[2], rl[3]};
        float4 L1 = {rl[4], rl[5], rl[6], rl[7]};
        float4 L2 = {rl[8], rl[9], rl[10], rl[11]};
        outv[qg * 3 + 0] = R0;
        outv[qg * 3 + 1] = R1;
        outv[qg * 3 + 2] = R2;
        outv[RO4 + qg * 3 + 0] = L0;
        outv[RO4 + qg * 3 + 1] = L1;
        outv[RO4 + qg * 3 + 2] = L2;
    }
}

extern "C" void kernel_launch(void* const* d_in, const int* in_sizes, int n_in,
                              void* d_out, int out_size, void* d_ws, size_t ws_size,
                              hipStream_t stream) {
    const float* proj = (const float*)d_in[0];
    const float* tex  = (const float*)d_in[1];
    const float* nbl  = (const float*)d_in[2];
    const float* ori  = (const float*)d_in[3];
    const int* vis    = (const int*)d_in[4];
    const int* tri    = (const int*)d_in[5];
    const int* pvalid = (const int*)d_in[6];
    float* out        = (float*)d_out;

    const size_t SHBYTES = (size_t)NVTOT * 16;         // 9.14 MB, 16B-aligned
    fvec4* shwv = (fvec4*)d_ws;
    char* accBase = (char*)d_ws + SHBYTES;

    const size_t perBatchBytes = (size_t)HWW * 8;      // 2 MiB / batch
    size_t remain = (ws_size > SHBYTES) ? ws_size - SHBYTES : 0;
    int nbMax = (int)(remain / perBatchBytes);
    if (nbMax < 1) nbMax = 1;
    if (nbMax > BB) nbMax = BB;

    for (int b0 = 0; b0 < BB; b0 += nbMax) {
        int nb = (BB - b0 < nbMax) ? (BB - b0) : nbMax;
        __half2* acc = (__half2*)accBase;

        long accN4 = (long)nb * HWW / 2;               // float4s to zero
        prep_kernel<<<2048, 256, 0, stream>>>(
            (const float4*)proj, (const float4*)tex, (const float4*)nbl,
            (const int4*)vis, shwv, (float4*)accBase, accN4);

        dim3 gs((NTT / 4 + 255) / 256, nb);
        splat_kernel<<<gs, 256, 0, stream>>>(shwv, (const int4*)tri, acc, b0);

        compose_kernel<<<2048, 256, 0, stream>>>(
            (const float4*)accBase, (const float4*)ori, (const int4*)pvalid,
            (float4*)out, b0, nb);
    }
}

// Round 14
// 74.061 us; speedup vs baseline: 3.5173x; 1.0724x over previous
//
#include <hip/hip_runtime.h>
#include <hip/hip_fp16.h>

#define BB 16
#define HH 512
#define WW 512
#define NVV 35709
#define NTT 70000
#define HWW (HH * WW)
#define NVTOT (BB * NVV)          // 571344, divisible by 4

// World model (R0-R13, verified):
//   proj_geo, texture, nbl, ori_img : float32
//   is_visible, tri_inds, pixel_valid : int32
//   OUTPUT: float32, concatenated [render BHW3 | real BHW3]
//
// R13 post-mortem: regular stores beat NT by 16.4us (write-back absorbs the
// 201MB output in L3); compose now < 57.7us ~= its 302MB mixed-stream floor.
// R14: accumulator 8B -> 4B/px, fixed-point packed u32 {w:5|b:9|g:9|r:9},
// colors x64. One atomicAdd(u32) per visible triangle. Field overflow safe:
// per-pixel hits Poisson(lambda<=0.12) -> P(>=8) ~ 1e-10; w<=31, csum<=7.98.
// Quantization 1/128 ~= 0.008 after /w, threshold 2e-2.
//
// ws layout: VRec shw[NVTOT] (16 B/vertex: f32 x, f32 y, f16 rg, f16 b|vis)
//            u32 acc[nb*HW] (4 B/pixel)

typedef float fvec4 __attribute__((ext_vector_type(4)));

struct VRec { float x, y; __half2 rg; __half2 bv; };   // 16 B

#define CSCALE 64.0f
#define CINV   0.015625f          // 1/64
#define RMASK  511u

// ---------------------------------------------------------------------------
// prep: grid-stride. (a) zero acc region (u32/px), (b) build 16B vertex
// records. Positions bit-exact f32; colors tex*nbl rounded to f16.
// ---------------------------------------------------------------------------
__global__ __launch_bounds__(256) void prep_kernel(
    const float4* __restrict__ proj4,
    const float4* __restrict__ tex4,
    const float4* __restrict__ nbl4,
    const int4* __restrict__ vis4,
    fvec4* __restrict__ shwv,
    float4* __restrict__ accz, long accN4)
{
    long tid = (long)blockIdx.x * blockDim.x + threadIdx.x;
    long stride = (long)gridDim.x * blockDim.x;

    float4 z = {0.f, 0.f, 0.f, 0.f};
    for (long i = tid; i < accN4; i += stride) accz[i] = z;

    for (long q = tid; q < NVTOT / 4; q += stride) {
        float4 P0 = proj4[q * 3 + 0], P1 = proj4[q * 3 + 1], P2 = proj4[q * 3 + 2];
        float4 T0 = tex4[q * 3 + 0], T1 = tex4[q * 3 + 1], T2 = tex4[q * 3 + 2];
        float4 N0 = nbl4[q * 3 + 0], N1 = nbl4[q * 3 + 1], N2 = nbl4[q * 3 + 2];
        int4 V = vis4[q];

        VRec r0, r1, r2, r3;
        r0.x = P0.x; r0.y = P0.y;
        r0.rg = __floats2half2_rn(T0.x * N0.x, T0.y * N0.y);
        r0.bv = __floats2half2_rn(T0.z * N0.z, V.x ? 1.f : 0.f);
        r1.x = P0.w; r1.y = P1.x;
        r1.rg = __floats2half2_rn(T0.w * N0.w, T1.x * N1.x);
        r1.bv = __floats2half2_rn(T1.y * N1.y, V.y ? 1.f : 0.f);
        r2.x = P1.z; r2.y = P1.w;
        r2.rg = __floats2half2_rn(T1.z * N1.z, T1.w * N1.w);
        r2.bv = __floats2half2_rn(T2.x * N2.x, V.z ? 1.f : 0.f);
        r3.x = P2.y; r3.y = P2.z;
        r3.rg = __floats2half2_rn(T2.y * N2.y, T2.z * N2.z);
        r3.bv = __floats2half2_rn(T2.w * N2.w, V.w ? 1.f : 0.f);

        shwv[q * 4 + 0] = __builtin_bit_cast(fvec4, r0);
        shwv[q * 4 + 1] = __builtin_bit_cast(fvec4, r1);
        shwv[q * 4 + 2] = __builtin_bit_cast(fvec4, r2);
        shwv[q * 4 + 3] = __builtin_bit_cast(fvec4, r3);
    }
}

// ---------------------------------------------------------------------------
// splat: 4 triangles/thread; 3 int4 index loads + 12 x 16B record gathers,
// then per-tri vis gate + centroid + ONE packed u32 atomic.
// ---------------------------------------------------------------------------
__global__ __launch_bounds__(256) void splat_kernel(
    const fvec4* __restrict__ shwv,
    const int4* __restrict__ tri4,    // [NTT*3/4]
    unsigned int* __restrict__ acc,
    int b0)
{
    int g = blockIdx.x * blockDim.x + threadIdx.x;   // 4-triangle group
    if (g >= NTT / 4) return;                        // 17500 groups
    int bl = blockIdx.y;
    int base = (b0 + bl) * NVV;

    int4 wA = tri4[g * 3 + 0];
    int4 wB = tri4[g * 3 + 1];
    int4 wC = tri4[g * 3 + 2];
    int idx[12] = {wA.x, wA.y, wA.z, wA.w, wB.x, wB.y, wB.z, wB.w,
                   wC.x, wC.y, wC.z, wC.w};

    fvec4 vr[12];
#pragma unroll
    for (int k = 0; k < 12; ++k) vr[k] = shwv[base + idx[k]];

    long paccb = (long)bl * HWW;
#pragma unroll
    for (int k = 0; k < 4; ++k) {
        VRec s0 = __builtin_bit_cast(VRec, vr[k * 3 + 0]);
        VRec s1 = __builtin_bit_cast(VRec, vr[k * 3 + 1]);
        VRec s2 = __builtin_bit_cast(VRec, vr[k * 3 + 2]);

        // tri_w = min(vis): any invisible vertex kills the splat
        if (__high2float(s0.bv) == 0.f || __high2float(s1.bv) == 0.f ||
            __high2float(s2.bv) == 0.f) continue;

        float fx = ((s0.x + s1.x) + s2.x) / 3.0f;   // numpy f32 semantics
        float fy = ((s0.y + s1.y) + s2.y) / 3.0f;
        int px = (int)rintf(fx);                    // round-half-even
        int py = (int)rintf(fy);
        px = min(max(px, 0), WW - 1);
        py = min(max(py, 0), HH - 1);

        float cr = ((__low2float(s0.rg) + __low2float(s1.rg)) + __low2float(s2.rg)) / 3.0f;
        float cg = ((__high2float(s0.rg) + __high2float(s1.rg)) + __high2float(s2.rg)) / 3.0f;
        float cb = ((__low2float(s0.bv) + __low2float(s1.bv)) + __low2float(s2.bv)) / 3.0f;

        unsigned rq = (unsigned)(cr * CSCALE + 0.5f);
        unsigned gq = (unsigned)(cg * CSCALE + 0.5f);
        unsigned bq = (unsigned)(cb * CSCALE + 0.5f);
        unsigned pk = rq | (gq << 9) | (bq << 18) | (1u << 27);

        long lin = paccb + (long)py * WW + px;
        atomicAdd(&acc[lin], pk);
    }
}

// ---------------------------------------------------------------------------
// compose: 4px/thread grid-stride, cached loads, plain cached float4 stores.
// acc: one int4 load per 4 pixels.
// ---------------------------------------------------------------------------
__global__ __launch_bounds__(256) void compose_kernel(
    const int4* __restrict__ accv,       // packed u32/px, 4 px per int4
    const float4* __restrict__ oriv,
    const int4* __restrict__ pvv,
    float4* __restrict__ outv,
    int b0, int nb)
{
    long ngrp = (long)nb * (HWW / 4);
    long stride = (long)gridDim.x * blockDim.x;
    const long RO4 = (long)BB * HWW * 3 / 4;   // `real` offset in float4 units

    for (long q = (long)blockIdx.x * blockDim.x + threadIdx.x; q < ngrp;
         q += stride) {
        long qg = (long)b0 * (HWW / 4) + q;                 // global group

        int4 A = accv[q];
        int4 PV = pvv[qg];
        float4 O0 = oriv[qg * 3 + 0];
        float4 O1 = oriv[qg * 3 + 1];
        float4 O2 = oriv[qg * 3 + 2];

        float of[12] = {O0.x, O0.y, O0.z, O0.w, O1.x, O1.y, O1.z, O1.w,
                        O2.x, O2.y, O2.z, O2.w};
        unsigned av[4] = {(unsigned)A.x, (unsigned)A.y,
                          (unsigned)A.z, (unsigned)A.w};
        int pva[4] = {PV.x, PV.y, PV.z, PV.w};

        float rd[12], rl[12];
#pragma unroll
        for (int p = 0; p < 4; ++p) {
            unsigned a = av[p];
            unsigned w = a >> 27;
            bool pv = pva[p] > 0;
            bool cov = (w > 0u) && pv;
            float dninv = cov ? (1.0f / (float)w) : 0.0f;
            float fr = (float)(a & RMASK) * CINV * dninv;
            float fg = (float)((a >> 9) & RMASK) * CINV * dninv;
            float fb = (float)((a >> 18) & RMASK) * CINV * dninv;
            rd[p * 3 + 0] = cov ? fr : of[p * 3 + 0];
            rd[p * 3 + 1] = cov ? fg : of[p * 3 + 1];
            rd[p * 3 + 2] = cov ? fb : of[p * 3 + 2];
            rl[p * 3 + 0] = pv ? of[p * 3 + 0] : 0.f;
            rl[p * 3 + 1] = pv ? of[p * 3 + 1] : 0.f;
            rl[p * 3 + 2] = pv ? of[p * 3 + 2] : 0.f;
        }

        float4 R0 = {rd[0], rd[1], rd[2], rd[3]};
        float4 R1 = {rd[4], rd[5], rd[6], rd[7]};
        float4 R2 = {rd[8], rd[9], rd[10], rd[11]};
        float4 L0 = {rl[0], rl[1], rl[2], rl[3]};
        float4 L1 = {rl[4], rl[5], rl[6], rl[7]};
        float4 L2 = {rl[8], rl[9], rl[10], rl[11]};
        outv[qg * 3 + 0] = R0;
        outv[qg * 3 + 1] = R1;
        outv[qg * 3 + 2] = R2;
        outv[RO4 + qg * 3 + 0] = L0;
        outv[RO4 + qg * 3 + 1] = L1;
        outv[RO4 + qg * 3 + 2] = L2;
    }
}

extern "C" void kernel_launch(void* const* d_in, const int* in_sizes, int n_in,
                              void* d_out, int out_size, void* d_ws, size_t ws_size,
                              hipStream_t stream) {
    const float* proj = (const float*)d_in[0];
    const float* tex  = (const float*)d_in[1];
    const float* nbl  = (const float*)d_in[2];
    const float* ori  = (const float*)d_in[3];
    const int* vis    = (const int*)d_in[4];
    const int* tri    = (const int*)d_in[5];
    const int* pvalid = (const int*)d_in[6];
    float* out        = (float*)d_out;

    const size_t SHBYTES = (size_t)NVTOT * 16;         // 9.14 MB, 16B-aligned
    fvec4* shwv = (fvec4*)d_ws;
    char* accBase = (char*)d_ws + SHBYTES;

    const size_t perBatchBytes = (size_t)HWW * 4;      // 1 MiB / batch
    size_t remain = (ws_size > SHBYTES) ? ws_size - SHBYTES : 0;
    int nbMax = (int)(remain / perBatchBytes);
    if (nbMax < 1) nbMax = 1;
    if (nbMax > BB) nbMax = BB;

    for (int b0 = 0; b0 < BB; b0 += nbMax) {
        int nb = (BB - b0 < nbMax) ? (BB - b0) : nbMax;
        unsigned int* acc = (unsigned int*)accBase;

        long accN4 = (long)nb * HWW / 4;               // float4s to zero (4B/px)
        prep_kernel<<<2048, 256, 0, stream>>>(
            (const float4*)proj, (const float4*)tex, (const float4*)nbl,
            (const int4*)vis, shwv, (float4*)accBase, accN4);

        dim3 gs((NTT / 4 + 255) / 256, nb);
        splat_kernel<<<gs, 256, 0, stream>>>(shwv, (const int4*)tri, acc, b0);

        compose_kernel<<<2048, 256, 0, stream>>>(
            (const int4*)accBase, (const float4*)ori, (const int4*)pvalid,
            (float4*)out, b0, nb);
    }
}

// Round 15
// 71.018 us; speedup vs baseline: 3.6680x; 1.0429x over previous
//
#include <hip/hip_runtime.h>
#include <hip/hip_fp16.h>

#define BB 16
#define HH 512
#define WW 512
#define NVV 35709
#define NTT 70000
#define HWW (HH * WW)
#define NVTOT (BB * NVV)          // 571344, divisible by 4

// World model (R0-R14, verified):
//   proj_geo, texture, nbl, ori_img : float32
//   is_visible, tri_inds, pixel_valid : int32
//   OUTPUT: float32, concatenated [render BHW3 | real BHW3]
//
// R14 post-mortem (budget rebuilt): compose ~55us (at 335.6MB mixed floor),
// prep ~15us (at 104MB floor), splat ~2, gaps ~2. All BW-bound. R15: cut
// prep bytes - drop proj from the records (8B records {rg, b|vis}); splat
// gathers x,y straight from proj, GATED to all-visible triangles (~12.5%).
// Saves ~30MB in prep for ~+1us in splat.
//
// ws layout: Shaded shw[NVTOT] (8 B/vertex: f16 r,g,b, f16 vis)
//            u32 acc[nb*HW] (4 B/pixel, packed {w:5|b:9|g:9|r:9}, colors x64)

typedef float fvec4 __attribute__((ext_vector_type(4)));

struct Shaded { __half2 rg; __half2 bv; };   // 8 B
struct H4 { __half2 a, b, c, d; };           // 16 B = 2 records

#define CSCALE 64.0f
#define CINV   0.015625f          // 1/64
#define RMASK  511u

// ---------------------------------------------------------------------------
// prep: grid-stride. (a) zero acc region (u32/px), (b) build 8B shaded
// records (tex*nbl -> f16, vis flag in .w). No proj traffic.
// ---------------------------------------------------------------------------
__global__ __launch_bounds__(256) void prep_kernel(
    const float4* __restrict__ tex4,
    const float4* __restrict__ nbl4,
    const int4* __restrict__ vis4,
    fvec4* __restrict__ shw4,            // 2 records per fvec4
    float4* __restrict__ accz, long accN4)
{
    long tid = (long)blockIdx.x * blockDim.x + threadIdx.x;
    long stride = (long)gridDim.x * blockDim.x;

    float4 z = {0.f, 0.f, 0.f, 0.f};
    for (long i = tid; i < accN4; i += stride) accz[i] = z;

    for (long q = tid; q < NVTOT / 4; q += stride) {
        float4 T0 = tex4[q * 3 + 0], T1 = tex4[q * 3 + 1], T2 = tex4[q * 3 + 2];
        float4 N0 = nbl4[q * 3 + 0], N1 = nbl4[q * 3 + 1], N2 = nbl4[q * 3 + 2];
        int4 V = vis4[q];

        H4 lo, hi;
        lo.a = __floats2half2_rn(T0.x * N0.x, T0.y * N0.y);            // v0 rg
        lo.b = __floats2half2_rn(T0.z * N0.z, V.x ? 1.f : 0.f);        // v0 bv
        lo.c = __floats2half2_rn(T0.w * N0.w, T1.x * N1.x);            // v1 rg
        lo.d = __floats2half2_rn(T1.y * N1.y, V.y ? 1.f : 0.f);        // v1 bv
        hi.a = __floats2half2_rn(T1.z * N1.z, T1.w * N1.w);            // v2 rg
        hi.b = __floats2half2_rn(T2.x * N2.x, V.z ? 1.f : 0.f);        // v2 bv
        hi.c = __floats2half2_rn(T2.y * N2.y, T2.z * N2.z);            // v3 rg
        hi.d = __floats2half2_rn(T2.w * N2.w, V.w ? 1.f : 0.f);        // v3 bv

        shw4[q * 2 + 0] = __builtin_bit_cast(fvec4, lo);
        shw4[q * 2 + 1] = __builtin_bit_cast(fvec4, hi);
    }
}

// ---------------------------------------------------------------------------
// splat: 4 triangles/thread. 3 int4 index loads + 12 x 8B record gathers
// (ungated, MLP), then per-tri vis gate; SURVIVORS ONLY (~12.5%) load 6 f32
// positions from proj (bit-exact) + one packed u32 atomic.
// ---------------------------------------------------------------------------
__global__ __launch_bounds__(256) void splat_kernel(
    const float* __restrict__ proj,
    const float2* __restrict__ shw,
    const int4* __restrict__ tri4,    // [NTT*3/4]
    unsigned int* __restrict__ acc,
    int b0)
{
    int g = blockIdx.x * blockDim.x + threadIdx.x;   // 4-triangle group
    if (g >= NTT / 4) return;                        // 17500 groups
    int bl = blockIdx.y;
    int base = (b0 + bl) * NVV;

    int4 wA = tri4[g * 3 + 0];
    int4 wB = tri4[g * 3 + 1];
    int4 wC = tri4[g * 3 + 2];
    int idx[12] = {wA.x, wA.y, wA.z, wA.w, wB.x, wB.y, wB.z, wB.w,
                   wC.x, wC.y, wC.z, wC.w};

    float2 rec[12];
#pragma unroll
    for (int k = 0; k < 12; ++k) rec[k] = shw[base + idx[k]];

    long paccb = (long)bl * HWW;
#pragma unroll
    for (int k = 0; k < 4; ++k) {
        Shaded s0 = __builtin_bit_cast(Shaded, rec[k * 3 + 0]);
        Shaded s1 = __builtin_bit_cast(Shaded, rec[k * 3 + 1]);
        Shaded s2 = __builtin_bit_cast(Shaded, rec[k * 3 + 2]);

        // tri_w = min(vis): any invisible vertex kills the splat
        if (__high2float(s0.bv) == 0.f || __high2float(s1.bv) == 0.f ||
            __high2float(s2.bv) == 0.f) continue;

        // positions: gathered only for surviving triangles, raw f32
        long e0 = (long)(base + idx[k * 3 + 0]) * 3;
        long e1 = (long)(base + idx[k * 3 + 1]) * 3;
        long e2 = (long)(base + idx[k * 3 + 2]) * 3;
        float x0 = proj[e0], y0 = proj[e0 + 1];
        float x1 = proj[e1], y1 = proj[e1 + 1];
        float x2 = proj[e2], y2 = proj[e2 + 1];

        float fx = ((x0 + x1) + x2) / 3.0f;   // numpy f32 semantics
        float fy = ((y0 + y1) + y2) / 3.0f;
        int px = (int)rintf(fx);              // round-half-even
        int py = (int)rintf(fy);
        px = min(max(px, 0), WW - 1);
        py = min(max(py, 0), HH - 1);

        float cr = ((__low2float(s0.rg) + __low2float(s1.rg)) + __low2float(s2.rg)) / 3.0f;
        float cg = ((__high2float(s0.rg) + __high2float(s1.rg)) + __high2float(s2.rg)) / 3.0f;
        float cb = ((__low2float(s0.bv) + __low2float(s1.bv)) + __low2float(s2.bv)) / 3.0f;

        unsigned rq = (unsigned)(cr * CSCALE + 0.5f);
        unsigned gq = (unsigned)(cg * CSCALE + 0.5f);
        unsigned bq = (unsigned)(cb * CSCALE + 0.5f);
        unsigned pk = rq | (gq << 9) | (bq << 18) | (1u << 27);

        long lin = paccb + (long)py * WW + px;
        atomicAdd(&acc[lin], pk);
    }
}

// ---------------------------------------------------------------------------
// compose: 4px/thread grid-stride, cached loads, plain cached float4 stores.
// (R13/R14 proven structure — at its mixed-stream floor.)
// ---------------------------------------------------------------------------
__global__ __launch_bounds__(256) void compose_kernel(
    const int4* __restrict__ accv,       // packed u32/px, 4 px per int4
    const float4* __restrict__ oriv,
    const int4* __restrict__ pvv,
    float4* __restrict__ outv,
    int b0, int nb)
{
    long ngrp = (long)nb * (HWW / 4);
    long stride = (long)gridDim.x * blockDim.x;
    const long RO4 = (long)BB * HWW * 3 / 4;   // `real` offset in float4 units

    for (long q = (long)blockIdx.x * blockDim.x + threadIdx.x; q < ngrp;
         q += stride) {
        long qg = (long)b0 * (HWW / 4) + q;                 // global group

        int4 A = accv[q];
        int4 PV = pvv[qg];
        float4 O0 = oriv[qg * 3 + 0];
        float4 O1 = oriv[qg * 3 + 1];
        float4 O2 = oriv[qg * 3 + 2];

        float of[12] = {O0.x, O0.y, O0.z, O0.w, O1.x, O1.y, O1.z, O1.w,
                        O2.x, O2.y, O2.z, O2.w};
        unsigned av[4] = {(unsigned)A.x, (unsigned)A.y,
                          (unsigned)A.z, (unsigned)A.w};
        int pva[4] = {PV.x, PV.y, PV.z, PV.w};

        float rd[12], rl[12];
#pragma unroll
        for (int p = 0; p < 4; ++p) {
            unsigned a = av[p];
            unsigned w = a >> 27;
            bool pv = pva[p] > 0;
            bool cov = (w > 0u) && pv;
            float dninv = cov ? (1.0f / (float)w) : 0.0f;
            float fr = (float)(a & RMASK) * CINV * dninv;
            float fg = (float)((a >> 9) & RMASK) * CINV * dninv;
            float fb = (float)((a >> 18) & RMASK) * CINV * dninv;
            rd[p * 3 + 0] = cov ? fr : of[p * 3 + 0];
            rd[p * 3 + 1] = cov ? fg : of[p * 3 + 1];
            rd[p * 3 + 2] = cov ? fb : of[p * 3 + 2];
            rl[p * 3 + 0] = pv ? of[p * 3 + 0] : 0.f;
            rl[p * 3 + 1] = pv ? of[p * 3 + 1] : 0.f;
            rl[p * 3 + 2] = pv ? of[p * 3 + 2] : 0.f;
        }

        float4 R0 = {rd[0], rd[1], rd[2], rd[3]};
        float4 R1 = {rd[4], rd[5], rd[6], rd[7]};
        float4 R2 = {rd[8], rd[9], rd[10], rd[11]};
        float4 L0 = {rl[0], rl[1], rl[2], rl[3]};
        float4 L1 = {rl[4], rl[5], rl[6], rl[7]};
        float4 L2 = {rl[8], rl[9], rl[10], rl[11]};
        outv[qg * 3 + 0] = R0;
        outv[qg * 3 + 1] = R1;
        outv[qg * 3 + 2] = R2;
        outv[RO4 + qg * 3 + 0] = L0;
        outv[RO4 + qg * 3 + 1] = L1;
        outv[RO4 + qg * 3 + 2] = L2;
    }
}

extern "C" void kernel_launch(void* const* d_in, const int* in_sizes, int n_in,
                              void* d_out, int out_size, void* d_ws, size_t ws_size,
                              hipStream_t stream) {
    const float* proj = (const float*)d_in[0];
    const float* tex  = (const float*)d_in[1];
    const float* nbl  = (const float*)d_in[2];
    const float* ori  = (const float*)d_in[3];
    const int* vis    = (const int*)d_in[4];
    const int* tri    = (const int*)d_in[5];
    const int* pvalid = (const int*)d_in[6];
    float* out        = (float*)d_out;

    const size_t SHBYTES = (size_t)NVTOT * 8;          // 4.57 MB, 16B-aligned
    float2* shw = (float2*)d_ws;
    char* accBase = (char*)d_ws + SHBYTES;

    const size_t perBatchBytes = (size_t)HWW * 4;      // 1 MiB / batch
    size_t remain = (ws_size > SHBYTES) ? ws_size - SHBYTES : 0;
    int nbMax = (int)(remain / perBatchBytes);
    if (nbMax < 1) nbMax = 1;
    if (nbMax > BB) nbMax = BB;

    for (int b0 = 0; b0 < BB; b0 += nbMax) {
        int nb = (BB - b0 < nbMax) ? (BB - b0) : nbMax;
        unsigned int* acc = (unsigned int*)accBase;

        long accN4 = (long)nb * HWW / 4;               // float4s to zero (4B/px)
        prep_kernel<<<2048, 256, 0, stream>>>(
            (const float4*)tex, (const float4*)nbl, (const int4*)vis,
            (fvec4*)shw, (float4*)accBase, accN4);

        dim3 gs((NTT / 4 + 255) / 256, nb);
        splat_kernel<<<gs, 256, 0, stream>>>(proj, shw, (const int4*)tri, acc, b0);

        compose_kernel<<<2048, 256, 0, stream>>>(
            (const int4*)accBase, (const float4*)ori, (const int4*)pvalid,
            (float4*)out, b0, nb);
    }
}